// Round 2
// baseline (39288.266 us; speedup 1.0000x reference)
//
#include <hip/hip_runtime.h>
#include <math.h>

typedef unsigned short ushort_t;
typedef short short8 __attribute__((ext_vector_type(8)));
typedef float floatx4 __attribute__((ext_vector_type(4)));
typedef float float4v __attribute__((ext_vector_type(4)));

__device__ __forceinline__ float b2f(ushort_t u) {
    union { unsigned int i; float f; } v; v.i = ((unsigned int)u) << 16; return v.f;
}
__device__ __forceinline__ ushort_t f2b(float f) {
    union { float f; unsigned int i; } v; v.f = f;
    unsigned int x = v.i;
    return (ushort_t)((x + 0x7fffu + ((x >> 16) & 1u)) >> 16);  // RNE
}
__device__ __forceinline__ void split8(const float* v, short8& hi, short8& lo) {
#pragma unroll
    for (int e = 0; e < 8; ++e) {
        ushort_t h = f2b(v[e]);
        hi[e] = (short)h;
        lo[e] = (short)f2b(v[e] - b2f(h));
    }
}
__device__ __forceinline__ void load8f(const float* p, float* v) {
    *(float4v*)(v)     = *(const float4v*)(p);
    *(float4v*)(v + 4) = *(const float4v*)(p + 4);
}

// Classify input encoding. bf16 data: bits[14:7] of each u32 word is the low
// element's exponent field -> almost always in [100,140] for ~N(0,1) data.
// fp32 data: bits[14:7] are mantissa bits -> uniform, in-range ~16%.
__global__ void detect_dtype(const unsigned int* __restrict__ x, int* __restrict__ flag) {
    __shared__ int cnt;
    if (threadIdx.x == 0) cnt = 0;
    __syncthreads();
    int c = 0;
#pragma unroll
    for (int i = 0; i < 8; ++i) {
        unsigned int w = x[threadIdx.x * 8 + i];
        unsigned int e = (w >> 7) & 0xFFu;
        if (e >= 100u && e <= 140u) ++c;
    }
    atomicAdd(&cnt, c);
    __syncthreads();
    if (threadIdx.x == 0) *flag = (cnt > 1024) ? 1 : 0;   // 1 = bf16, 0 = f32
}

// One timestep, both directions. 64 WGs x 256 thr.
// d = bx>>5, j0 = (bx&31)*16; wave q computes gate q for cols [j0,j0+16).
// gates = [in_t | h_masked] @ [w_ih | w_hh]^T  via MFMA 16x16x32 bf16.
// fp32 path: hi/lo split compensated (3 MFMAs per tile).
template <int LAYER>
__global__ __launch_bounds__(256) void lstm_step(
    int s, int out0_f32_ok, int write_hn,
    const int* __restrict__ flag,
    const void* __restrict__ xin,     // L0: x [B,T,512]
    void* __restrict__ out0,          // out0 region: L0 writes (mask_out folded), L1 reads
    char* __restrict__ hbase,         // h double-buffer (mask_h folded), parity by step
    float* __restrict__ cbuf,         // [2,32,512] f32
    const void* __restrict__ w_ih,    // [2,2048,K1]
    const void* __restrict__ w_hh,    // [2,2048,512]
    const void* __restrict__ bias,    // [2,2048]
    const void* __restrict__ mask_x,  // [32,512]   (L0)
    const void* __restrict__ mask_h,  // [2,32,512] (base; layer offset inside)
    const void* __restrict__ mask_out,// [32,1024]  (L0)
    void* __restrict__ dout)          // d_out base
{
    __shared__ float gbuf[4][32][16];
    const int d    = blockIdx.x >> 5;
    const int j0   = (blockIdx.x & 31) << 4;
    const int t    = d ? (511 - s) : s;
    const int tid  = threadIdx.x;
    const int lane = tid & 63;
    const int q    = tid >> 6;
    const int n16  = lane & 15;
    const int quad = lane >> 4;
    const int koff = quad * 8;
    const int g    = q * 512 + j0 + n16;
    constexpr int K1 = (LAYER == 0) ? 512 : 1024;

    const bool isbf = (*flag != 0);
    floatx4 acc0 = {0.f, 0.f, 0.f, 0.f};
    floatx4 acc1 = {0.f, 0.f, 0.f, 0.f};

    if (isbf) {
        const ushort_t* WI  = (const ushort_t*)w_ih;
        const ushort_t* WH  = (const ushort_t*)w_hh;
        const ushort_t* bip = WI + ((size_t)d * 2048 + g) * K1 + koff;
        if (LAYER == 0) {
            const ushort_t* X  = (const ushort_t*)xin;
            const ushort_t* MX = (const ushort_t*)mask_x;
            const ushort_t* x0 = X + ((size_t)n16 * 512 + t) * 512 + koff;
            const ushort_t* x1 = X + ((size_t)(n16 + 16) * 512 + t) * 512 + koff;
            const ushort_t* m0 = MX + n16 * 512 + koff;
            const ushort_t* m1 = MX + (n16 + 16) * 512 + koff;
#pragma unroll 4
            for (int ki = 0; ki < 16; ++ki) {
                short8 xv0 = *(const short8*)(x0 + ki * 32);
                short8 xv1 = *(const short8*)(x1 + ki * 32);
                short8 mv0 = *(const short8*)(m0 + ki * 32);
                short8 mv1 = *(const short8*)(m1 + ki * 32);
                short8 bv  = *(const short8*)(bip + ki * 32);
                short8 a0, a1;
#pragma unroll
                for (int e = 0; e < 8; ++e) {
                    a0[e] = (short)f2b(b2f((ushort_t)xv0[e]) * b2f((ushort_t)mv0[e]));
                    a1[e] = (short)f2b(b2f((ushort_t)xv1[e]) * b2f((ushort_t)mv1[e]));
                }
                acc0 = __builtin_amdgcn_mfma_f32_16x16x32_bf16(a0, bv, acc0, 0, 0, 0);
                acc1 = __builtin_amdgcn_mfma_f32_16x16x32_bf16(a1, bv, acc1, 0, 0, 0);
            }
        } else {
            const ushort_t* P1 = (const ushort_t*)out0;
            const ushort_t* p0 = P1 + ((size_t)t * 32 + n16) * 1024 + koff;
            const ushort_t* p1 = p0 + 16 * 1024;
#pragma unroll 4
            for (int ki = 0; ki < 32; ++ki) {
                short8 a0 = *(const short8*)(p0 + ki * 32);
                short8 a1 = *(const short8*)(p1 + ki * 32);
                short8 bv = *(const short8*)(bip + ki * 32);
                acc0 = __builtin_amdgcn_mfma_f32_16x16x32_bf16(a0, bv, acc0, 0, 0, 0);
                acc1 = __builtin_amdgcn_mfma_f32_16x16x32_bf16(a1, bv, acc1, 0, 0, 0);
            }
        }
        const ushort_t* HR  = (const ushort_t*)hbase + (s & 1) * 32768;
        const ushort_t* h0  = HR + (d * 32 + n16) * 512 + koff;
        const ushort_t* h1  = h0 + 16 * 512;
        const ushort_t* bhp = WH + ((size_t)d * 2048 + g) * 512 + koff;
#pragma unroll 4
        for (int ki = 0; ki < 16; ++ki) {
            short8 a0 = *(const short8*)(h0 + ki * 32);
            short8 a1 = *(const short8*)(h1 + ki * 32);
            short8 bv = *(const short8*)(bhp + ki * 32);
            acc0 = __builtin_amdgcn_mfma_f32_16x16x32_bf16(a0, bv, acc0, 0, 0, 0);
            acc1 = __builtin_amdgcn_mfma_f32_16x16x32_bf16(a1, bv, acc1, 0, 0, 0);
        }
    } else {
        // ---------------- fp32 path: compensated bf16 MFMA ----------------
        const float* WIf  = (const float*)w_ih;
        const float* WHf  = (const float*)w_hh;
        const float* bipf = WIf + ((size_t)d * 2048 + g) * K1 + koff;
        float v0[8], v1[8], w[8], tmp[8];
        short8 a0h, a0l, a1h, a1l, bh, bl;
        if (LAYER == 0) {
            const float* Xf  = (const float*)xin;
            const float* MXf = (const float*)mask_x;
            const float* x0 = Xf + ((size_t)n16 * 512 + t) * 512 + koff;
            const float* x1 = Xf + ((size_t)(n16 + 16) * 512 + t) * 512 + koff;
            const float* m0 = MXf + n16 * 512 + koff;
            const float* m1 = MXf + (n16 + 16) * 512 + koff;
            for (int ki = 0; ki < 16; ++ki) {
                load8f(x0 + ki * 32, v0); load8f(m0 + ki * 32, tmp);
#pragma unroll
                for (int e = 0; e < 8; ++e) v0[e] *= tmp[e];
                load8f(x1 + ki * 32, v1); load8f(m1 + ki * 32, tmp);
#pragma unroll
                for (int e = 0; e < 8; ++e) v1[e] *= tmp[e];
                load8f(bipf + ki * 32, w);
                split8(v0, a0h, a0l); split8(v1, a1h, a1l); split8(w, bh, bl);
                acc0 = __builtin_amdgcn_mfma_f32_16x16x32_bf16(a0h, bh, acc0, 0, 0, 0);
                acc0 = __builtin_amdgcn_mfma_f32_16x16x32_bf16(a0l, bh, acc0, 0, 0, 0);
                acc0 = __builtin_amdgcn_mfma_f32_16x16x32_bf16(a0h, bl, acc0, 0, 0, 0);
                acc1 = __builtin_amdgcn_mfma_f32_16x16x32_bf16(a1h, bh, acc1, 0, 0, 0);
                acc1 = __builtin_amdgcn_mfma_f32_16x16x32_bf16(a1l, bh, acc1, 0, 0, 0);
                acc1 = __builtin_amdgcn_mfma_f32_16x16x32_bf16(a1h, bl, acc1, 0, 0, 0);
            }
        } else {
            for (int ki = 0; ki < 32; ++ki) {
                size_t i0 = ((size_t)t * 32 + n16) * 1024 + koff + ki * 32;
                size_t i1 = i0 + 16 * 1024;
                if (out0_f32_ok) {
                    load8f((const float*)out0 + i0, v0);
                    load8f((const float*)out0 + i1, v1);
                } else {
                    const ushort_t* P1 = (const ushort_t*)out0;
#pragma unroll
                    for (int e = 0; e < 8; ++e) { v0[e] = b2f(P1[i0 + e]); v1[e] = b2f(P1[i1 + e]); }
                }
                load8f(WIf + ((size_t)d * 2048 + g) * K1 + koff + ki * 32, w);
                split8(v0, a0h, a0l); split8(v1, a1h, a1l); split8(w, bh, bl);
                acc0 = __builtin_amdgcn_mfma_f32_16x16x32_bf16(a0h, bh, acc0, 0, 0, 0);
                acc0 = __builtin_amdgcn_mfma_f32_16x16x32_bf16(a0l, bh, acc0, 0, 0, 0);
                acc0 = __builtin_amdgcn_mfma_f32_16x16x32_bf16(a0h, bl, acc0, 0, 0, 0);
                acc1 = __builtin_amdgcn_mfma_f32_16x16x32_bf16(a1h, bh, acc1, 0, 0, 0);
                acc1 = __builtin_amdgcn_mfma_f32_16x16x32_bf16(a1l, bh, acc1, 0, 0, 0);
                acc1 = __builtin_amdgcn_mfma_f32_16x16x32_bf16(a1h, bl, acc1, 0, 0, 0);
            }
        }
        const float* HRf  = (const float*)hbase + (s & 1) * 32768;
        const float* h0   = HRf + (d * 32 + n16) * 512 + koff;
        const float* h1   = h0 + 16 * 512;
        const float* bhpf = WHf + ((size_t)d * 2048 + g) * 512 + koff;
        for (int ki = 0; ki < 16; ++ki) {
            load8f(h0 + ki * 32, v0);
            load8f(h1 + ki * 32, v1);
            load8f(bhpf + ki * 32, w);
            split8(v0, a0h, a0l); split8(v1, a1h, a1l); split8(w, bh, bl);
            acc0 = __builtin_amdgcn_mfma_f32_16x16x32_bf16(a0h, bh, acc0, 0, 0, 0);
            acc0 = __builtin_amdgcn_mfma_f32_16x16x32_bf16(a0l, bh, acc0, 0, 0, 0);
            acc0 = __builtin_amdgcn_mfma_f32_16x16x32_bf16(a0h, bl, acc0, 0, 0, 0);
            acc1 = __builtin_amdgcn_mfma_f32_16x16x32_bf16(a1h, bh, acc1, 0, 0, 0);
            acc1 = __builtin_amdgcn_mfma_f32_16x16x32_bf16(a1l, bh, acc1, 0, 0, 0);
            acc1 = __builtin_amdgcn_mfma_f32_16x16x32_bf16(a1h, bl, acc1, 0, 0, 0);
        }
    }

#pragma unroll
    for (int r = 0; r < 4; ++r) {
        gbuf[q][quad * 4 + r][n16]      = acc0[r];
        gbuf[q][16 + quad * 4 + r][n16] = acc1[r];
    }
    __syncthreads();

#pragma unroll
    for (int rep = 0; rep < 2; ++rep) {
        int idx = tid + rep * 256;
        int b = idx >> 4;
        int n = idx & 15;
        int j = j0 + n;
        float bi, bf, bg, bo, mh, mo = 0.f;
        if (isbf) {
            const ushort_t* BI = (const ushort_t*)bias;
            const ushort_t* MH = (const ushort_t*)mask_h + LAYER * 16384;
            bi = b2f(BI[d * 2048 + j]);        bf = b2f(BI[d * 2048 + 512 + j]);
            bg = b2f(BI[d * 2048 + 1024 + j]); bo = b2f(BI[d * 2048 + 1536 + j]);
            mh = b2f(MH[b * 512 + j]);
            if (LAYER == 0) mo = b2f(((const ushort_t*)mask_out)[b * 1024 + d * 512 + j]);
        } else {
            const float* BI = (const float*)bias;
            const float* MH = (const float*)mask_h + LAYER * 16384;
            bi = BI[d * 2048 + j];        bf = BI[d * 2048 + 512 + j];
            bg = BI[d * 2048 + 1024 + j]; bo = BI[d * 2048 + 1536 + j];
            mh = MH[b * 512 + j];
            if (LAYER == 0) mo = ((const float*)mask_out)[b * 1024 + d * 512 + j];
        }
        float ig = gbuf[0][b][n] + bi;
        float fg = gbuf[1][b][n] + bf;
        float gg = gbuf[2][b][n] + bg;
        float og = gbuf[3][b][n] + bo;
        float co = cbuf[(d * 32 + b) * 512 + j];
        float si = 1.f / (1.f + expf(-ig));
        float sf = 1.f / (1.f + expf(-fg));
        float so = 1.f / (1.f + expf(-og));
        float cn = sf * co + si * tanhf(gg);
        float h  = so * tanhf(cn);
        cbuf[(d * 32 + b) * 512 + j] = cn;

        size_t o0 = ((size_t)t * 32 + b) * 1024 + d * 512 + j;      // out0 [T,B,1024]
        size_t o1 = ((size_t)b * 512 + t) * 1024 + d * 512 + j;     // d_out [B,T,1024]
        size_t hn = 16777216u + (size_t)((LAYER * 2 + d) * 32 + b) * 512 + j;
        if (isbf) {
            ushort_t* HW = (ushort_t*)hbase + ((s + 1) & 1) * 32768;
            HW[(d * 32 + b) * 512 + j] = f2b(h * mh);
            if (LAYER == 0) ((ushort_t*)out0)[o0] = f2b(h * mo);
            else            ((ushort_t*)dout)[o1] = f2b(h);
            if (s == 511 && write_hn) {
                ((ushort_t*)dout)[hn]         = f2b(h);
                ((ushort_t*)dout)[hn + 65536] = f2b(cn);
            }
        } else {
            float* HW = (float*)hbase + ((s + 1) & 1) * 32768;
            HW[(d * 32 + b) * 512 + j] = h * mh;
            if (LAYER == 0) {
                float ho = h * mo;
                if (out0_f32_ok) ((float*)out0)[o0] = ho;
                else             ((ushort_t*)out0)[o0] = f2b(ho);
            } else {
                ((float*)dout)[o1] = h;
            }
            if (s == 511 && write_hn) {
                ((float*)dout)[hn]         = h;
                ((float*)dout)[hn + 65536] = cn;
            }
        }
    }
}

extern "C" void kernel_launch(void* const* d_in, const int* in_sizes, int n_in,
                              void* d_out, int out_size, void* d_ws, size_t ws_size,
                              hipStream_t stream) {
    char* ws = (char*)d_ws;
    // ws layout: [out0 region][hbuf 256KB][cbuf 128KB][flag]
    int out0_f32_ok = (ws_size >= 67108864ull + 262144 + 131072 + 256) ? 1 : 0;
    size_t out0_bytes = out0_f32_ok ? 67108864ull : 33554432ull;
    char*  hbase = ws + out0_bytes;
    float* cbuf  = (float*)(hbase + 262144);
    int*   flag  = (int*)(hbase + 262144 + 131072);
    int write_hn = (out_size >= 16908288) ? 1 : 0;

    detect_dtype<<<1, 256, 0, stream>>>((const unsigned int*)d_in[0], flag);
    hipMemsetAsync(hbase, 0, 262144 + 131072, stream);   // h = c = 0

    for (int s = 0; s < 512; ++s)
        lstm_step<0><<<64, 256, 0, stream>>>(s, out0_f32_ok, write_hn, flag,
            d_in[0], ws, hbase, cbuf,
            d_in[4], d_in[5], d_in[6],
            d_in[1], d_in[3], d_in[2], d_out);

    hipMemsetAsync(hbase, 0, 262144 + 131072, stream);   // reset h, c for layer 1

    for (int s = 0; s < 512; ++s)
        lstm_step<1><<<64, 256, 0, stream>>>(s, out0_f32_ok, write_hn, flag,
            nullptr, ws, hbase, cbuf,
            d_in[7], d_in[8], d_in[9],
            nullptr, d_in[3], nullptr, d_out);
}